// Round 13
// baseline (45.674 us; speedup 1.0000x reference)
//
#include <hip/hip_runtime.h>
#include <hip/hip_bf16.h>

// YOLO layer decode: x (16, 340, 76, 76) f32 -> out (16, 4*76*76, 85) f32.
// Round 11 structure (best: 40.86 us): 2 y-rows per block, 1024 thr,
// bijective chunked XCD swizzle. Single variable this round: output stores
// via inline-asm global_store_dwordx4 sc0 sc1 nt (system-scope streaming,
// no L2/L3 allocate) so the write stream stops evicting the input from L3
// (input+output = 248 MB vs 256 MB L3; FETCH=61.5MB shows half-eviction).

constexpr int BS = 16;
constexpr int NA = 4;
constexpr int NC = 85;
constexpr int FY = 76;
constexpr int FX = 76;
constexpr int PLANE = FY * FX;        // 5776
constexpr int TILE  = NC * FX;        // 6460 floats per slab (one y)
constexpr int YG    = 2;              // y rows per block
constexpr int CHUNK = YG * FX;        // 152 floats contiguous per channel
constexpr int RVC   = CHUNK / 4;      // 38 float4s per channel chunk
constexpr int NV2   = NC * RVC;       // 3230 float4s per block
constexpr int NTHR  = 1024;
constexpr int KFULL = NV2 / NTHR;     // 3 full passes
constexpr int TAIL2 = NV2 - KFULL * NTHR;   // 158 (threads 0..157)
constexpr int NBLK  = BS * NA * (FY / YG);  // 2432
constexpr int PER_XCD = NBLK / 8;     // 304
constexpr float STRIDE_F = 8.0f;
constexpr float LOG2E = 1.4426950408889634f;

typedef float f32x4 __attribute__((ext_vector_type(4)));

__device__ __forceinline__ float fast_sigmoid(float v) {
    return __builtin_amdgcn_rcpf(1.0f + __builtin_amdgcn_exp2f(v * -LOG2E));
}
__device__ __forceinline__ float fast_exp(float v) {
    return __builtin_amdgcn_exp2f(v * LOG2E);
}

// Streaming store: system-scope, non-temporal -> no L2/L3 allocation.
__device__ __forceinline__ void store_stream(f32x4* p, f32x4 v) {
    asm volatile("global_store_dwordx4 %0, %1, off sc0 sc1 nt"
                 :: "v"(p), "v"(v) : "memory");
}

// Transform one float4 of channel c at quad j (j in [0,38)), scatter to
// lds[pos][c] where pos = 4j..4j+3 spans the 2-row x-range.
__device__ __forceinline__ void xform_scatter(float* __restrict__ lds,
                                              int c, int j, float4 v,
                                              float ax, float ay, float y0f) {
    const float vv[4] = {v.x, v.y, v.z, v.w};
    const int pos0 = 4 * j;
    const int ylocal = (j >= RVC / 2) ? 1 : 0;   // 76/4=19: quad never straddles rows
    const int xi0 = pos0 - ylocal * FX;
    float* __restrict__ dst = &lds[pos0 * NC + c];
    if (c >= 4) {
        #pragma unroll
        for (int kk = 0; kk < 4; ++kk)
            dst[kk * NC] = fast_sigmoid(vv[kk]);
    } else if (c == 0) {
        #pragma unroll
        for (int kk = 0; kk < 4; ++kk)
            dst[kk * NC] = fast_sigmoid(vv[kk]) * STRIDE_F
                         + (float)(xi0 + kk) * STRIDE_F;
    } else if (c == 1) {
        const float yf = y0f + (float)ylocal;
        #pragma unroll
        for (int kk = 0; kk < 4; ++kk)
            dst[kk * NC] = fast_sigmoid(vv[kk]) * STRIDE_F + yf * STRIDE_F;
    } else if (c == 2) {
        #pragma unroll
        for (int kk = 0; kk < 4; ++kk)
            dst[kk * NC] = fast_exp(vv[kk]) * ax;
    } else {
        #pragma unroll
        for (int kk = 0; kk < 4; ++kk)
            dst[kk * NC] = fast_exp(vv[kk]) * ay;
    }
}

__global__ __launch_bounds__(NTHR)
void yolo_decode_kernel(const float* __restrict__ x,
                        const float* __restrict__ anchors,
                        float* __restrict__ out) {
    __shared__ float lds[NC * CHUNK];   // 12920 floats = 51680 B

    const int B    = blockIdx.x;
    const int orig = (B & 7) * PER_XCD + (B >> 3);
    const int yp   = orig % (FY / YG);
    const int ba   = orig / (FY / YG);
    const int a    = ba % NA;

    const float ax  = anchors[a * 2 + 0] * STRIDE_F;
    const float ay  = anchors[a * 2 + 1] * STRIDE_F;
    const float y0f = (float)(YG * yp);

    const float* __restrict__ inbase = x + (size_t)ba * NC * PLANE + (size_t)yp * CHUNK;
    const int t = threadIdx.x;

    // --- Load phase: issue all 3-4 loads back-to-back. ---
    float4 v[KFULL + 1];
    #pragma unroll
    for (int k = 0; k < KFULL; ++k) {
        const int i = t + NTHR * k;
        const int c = i / RVC;            // magic-mul
        const int j = i - c * RVC;
        v[k] = *(const float4*)(inbase + (size_t)c * PLANE + j * 4);
    }
    if (t < TAIL2) {
        const int i = KFULL * NTHR + t;
        const int c = i / RVC;
        const int j = i - c * RVC;
        v[KFULL] = *(const float4*)(inbase + (size_t)c * PLANE + j * 4);
    }

    asm volatile("" ::: "memory");   // keep loads grouped above the transforms

    // --- Transform + LDS scatter. ---
    #pragma unroll
    for (int k = 0; k < KFULL; ++k) {
        const int i = t + NTHR * k;
        const int c = i / RVC;
        const int j = i - c * RVC;
        xform_scatter(lds, c, j, v[k], ax, ay, y0f);
    }
    if (t < TAIL2) {
        const int i = KFULL * NTHR + t;
        const int c = i / RVC;
        const int j = i - c * RVC;
        xform_scatter(lds, c, j, v[KFULL], ax, ay, y0f);
    }

    __syncthreads();

    // --- Store: 2 slabs = 12920 contiguous floats, streaming (no-alloc). ---
    const f32x4* __restrict__ ldsv = (const f32x4*)lds;
    f32x4* __restrict__ ov = (f32x4*)(out + (size_t)(ba * FY + YG * yp) * TILE);
    #pragma unroll
    for (int k = 0; k < KFULL; ++k)
        store_stream(&ov[t + NTHR * k], ldsv[t + NTHR * k]);
    if (t < TAIL2)
        store_stream(&ov[KFULL * NTHR + t], ldsv[KFULL * NTHR + t]);
}

extern "C" void kernel_launch(void* const* d_in, const int* in_sizes, int n_in,
                              void* d_out, int out_size, void* d_ws, size_t ws_size,
                              hipStream_t stream) {
    const float* x       = (const float*)d_in[0];
    const float* anchors = (const float*)d_in[1];
    float* out           = (float*)d_out;

    yolo_decode_kernel<<<NBLK, NTHR, 0, stream>>>(x, anchors, out);
}

// Round 14
// 41.022 us; speedup vs baseline: 1.1134x; 1.1134x over previous
//
#include <hip/hip_runtime.h>
#include <hip/hip_bf16.h>

// YOLO layer decode: x (16, 340, 76, 76) f32 -> out (16, 4*76*76, 85) f32.
// FINAL (revert to round-11 best, 40.86 us): 2 y-rows per block (608B read
// chunks, 51.7KB contiguous store run), bijective chunked XCD swizzle
// (memory-adjacent blocks share one XCD's L2), 1024 threads, float4 loads,
// fast transcendentals (v_exp_f32/v_rcp_f32), LDS transpose [c][x]->[x][c].
//
// Probed-to-neutral/regressed in rounds 7-13 (do not re-try):
//  - deeper MLP / load-group fences (VGPR verified up, dur flat)
//  - occupancy 49->64% via NTHR (flat); YG=4 alignment (regressed, -5%)
//  - __builtin_nontemporal_store and asm sc0/sc1/nt streaming stores
//    (FETCH_SIZE unchanged => no L3 allocation steering on gfx950 stores;
//    asm variant regressed ~12%)
// State: ~184 MB/replay @ 4.5 TB/s = 72% of 6.29 TB/s copy ceiling,
// traffic near-minimal (fetch 61.5 MB < input size due to L3 retention).

constexpr int BS = 16;
constexpr int NA = 4;
constexpr int NC = 85;
constexpr int FY = 76;
constexpr int FX = 76;
constexpr int PLANE = FY * FX;        // 5776
constexpr int TILE  = NC * FX;        // 6460 floats per slab (one y)
constexpr int YG    = 2;              // y rows per block
constexpr int CHUNK = YG * FX;        // 152 floats contiguous per channel
constexpr int RVC   = CHUNK / 4;      // 38 float4s per channel chunk
constexpr int NV2   = NC * RVC;       // 3230 float4s per block
constexpr int NTHR  = 1024;
constexpr int KFULL = NV2 / NTHR;     // 3 full passes
constexpr int TAIL2 = NV2 - KFULL * NTHR;   // 158 (threads 0..157)
constexpr int NBLK  = BS * NA * (FY / YG);  // 2432
constexpr int PER_XCD = NBLK / 8;     // 304 = 8 ba-panels x 38 ypairs
constexpr float STRIDE_F = 8.0f;
constexpr float LOG2E = 1.4426950408889634f;

__device__ __forceinline__ float fast_sigmoid(float v) {
    return __builtin_amdgcn_rcpf(1.0f + __builtin_amdgcn_exp2f(v * -LOG2E));
}
__device__ __forceinline__ float fast_exp(float v) {
    return __builtin_amdgcn_exp2f(v * LOG2E);
}

// Transform one float4 of channel c at quad j (j in [0,38)), scatter to
// lds[pos][c] where pos = 4j..4j+3 spans the 2-row x-range.
__device__ __forceinline__ void xform_scatter(float* __restrict__ lds,
                                              int c, int j, float4 v,
                                              float ax, float ay, float y0f) {
    const float vv[4] = {v.x, v.y, v.z, v.w};
    const int pos0 = 4 * j;
    const int ylocal = (j >= RVC / 2) ? 1 : 0;   // 76/4=19: quad never straddles rows
    const int xi0 = pos0 - ylocal * FX;
    float* __restrict__ dst = &lds[pos0 * NC + c];
    if (c >= 4) {
        #pragma unroll
        for (int kk = 0; kk < 4; ++kk)
            dst[kk * NC] = fast_sigmoid(vv[kk]);
    } else if (c == 0) {
        #pragma unroll
        for (int kk = 0; kk < 4; ++kk)
            dst[kk * NC] = fast_sigmoid(vv[kk]) * STRIDE_F
                         + (float)(xi0 + kk) * STRIDE_F;
    } else if (c == 1) {
        const float yf = y0f + (float)ylocal;
        #pragma unroll
        for (int kk = 0; kk < 4; ++kk)
            dst[kk * NC] = fast_sigmoid(vv[kk]) * STRIDE_F + yf * STRIDE_F;
    } else if (c == 2) {
        #pragma unroll
        for (int kk = 0; kk < 4; ++kk)
            dst[kk * NC] = fast_exp(vv[kk]) * ax;
    } else {
        #pragma unroll
        for (int kk = 0; kk < 4; ++kk)
            dst[kk * NC] = fast_exp(vv[kk]) * ay;
    }
}

__global__ __launch_bounds__(NTHR)
void yolo_decode_kernel(const float* __restrict__ x,
                        const float* __restrict__ anchors,
                        float* __restrict__ out) {
    __shared__ float lds[NC * CHUNK];   // 12920 floats = 51680 B

    // Bijective chunked XCD swizzle: XCD k (= blockIdx%8 round-robin) gets
    // orig in [k*304,(k+1)*304) = 8 whole ba panels, y-pairs in order.
    const int B    = blockIdx.x;
    const int orig = (B & 7) * PER_XCD + (B >> 3);
    const int yp   = orig % (FY / YG);
    const int ba   = orig / (FY / YG);
    const int a    = ba % NA;

    const float ax  = anchors[a * 2 + 0] * STRIDE_F;
    const float ay  = anchors[a * 2 + 1] * STRIDE_F;
    const float y0f = (float)(YG * yp);

    const float* __restrict__ inbase = x + (size_t)ba * NC * PLANE + (size_t)yp * CHUNK;
    const int t = threadIdx.x;

    // --- Load phase: issue all 3-4 loads back-to-back. ---
    float4 v[KFULL + 1];
    #pragma unroll
    for (int k = 0; k < KFULL; ++k) {
        const int i = t + NTHR * k;
        const int c = i / RVC;            // magic-mul
        const int j = i - c * RVC;
        v[k] = *(const float4*)(inbase + (size_t)c * PLANE + j * 4);
    }
    if (t < TAIL2) {
        const int i = KFULL * NTHR + t;
        const int c = i / RVC;
        const int j = i - c * RVC;
        v[KFULL] = *(const float4*)(inbase + (size_t)c * PLANE + j * 4);
    }

    asm volatile("" ::: "memory");   // keep loads grouped above the transforms

    // --- Transform + LDS scatter. ---
    #pragma unroll
    for (int k = 0; k < KFULL; ++k) {
        const int i = t + NTHR * k;
        const int c = i / RVC;
        const int j = i - c * RVC;
        xform_scatter(lds, c, j, v[k], ax, ay, y0f);
    }
    if (t < TAIL2) {
        const int i = KFULL * NTHR + t;
        const int c = i / RVC;
        const int j = i - c * RVC;
        xform_scatter(lds, c, j, v[KFULL], ax, ay, y0f);
    }

    __syncthreads();

    // --- Store: 2 slabs = 12920 contiguous floats (3230 float4s). ---
    const float4* __restrict__ ldsv = (const float4*)lds;
    float4* __restrict__ ov = (float4*)(out + (size_t)(ba * FY + YG * yp) * TILE);
    #pragma unroll
    for (int k = 0; k < KFULL; ++k)
        ov[t + NTHR * k] = ldsv[t + NTHR * k];
    if (t < TAIL2)
        ov[KFULL * NTHR + t] = ldsv[KFULL * NTHR + t];
}

extern "C" void kernel_launch(void* const* d_in, const int* in_sizes, int n_in,
                              void* d_out, int out_size, void* d_ws, size_t ws_size,
                              hipStream_t stream) {
    const float* x       = (const float*)d_in[0];
    const float* anchors = (const float*)d_in[1];
    float* out           = (float*)d_out;

    yolo_decode_kernel<<<NBLK, NTHR, 0, stream>>>(x, anchors, out);
}